// Round 1
// baseline (1371.042 us; speedup 1.0000x reference)
//
#include <hip/hip_runtime.h>
#include <stdint.h>

#define COLS 16384
#define TPB 1024
#define EPT (COLS / TPB)        // 16 elements per thread
#define F4PT (COLS / 4 / TPB)   // 4 float4 per thread
#define MAXR 40

// Order-preserving float -> u32 key map (monotone bijection over non-NaN).
__device__ __forceinline__ unsigned f2k(unsigned u) {
    return (u & 0x80000000u) ? ~u : (u | 0x80000000u);
}
__device__ __forceinline__ float k2f(unsigned kk) {
    unsigned u = (kk & 0x80000000u) ? (kk ^ 0x80000000u) : ~kk;
    return __uint_as_float(u);
}

__global__ __launch_bounds__(TPB, 8) void topk_row_kernel(
        const float* __restrict__ x,
        const int* __restrict__ kptr,
        float* __restrict__ out) {
    const int tid = threadIdx.x;
    const size_t base = (size_t)blockIdx.x * (size_t)COLS;
    const float4* __restrict__ xin  = (const float4*)(x + base);
    float4*       __restrict__ xout = (float4*)(out + base);
    const int k = kptr[0];

    // Round-indexed packed counters: c1 | c2<<21 | c3<<42 (each sum <= 16384*16 < 2^21).
    __shared__ unsigned long long cnts[MAXR];
    if (tid < MAXR) cnts[tid] = 0ull;

    // Load 16 elements/thread, coalesced float4, convert to sortable keys.
    unsigned key[EPT];
#pragma unroll
    for (int i = 0; i < F4PT; ++i) {
        float4 v = xin[i * TPB + tid];
        key[i*4+0] = f2k(__float_as_uint(v.x));
        key[i*4+1] = f2k(__float_as_uint(v.y));
        key[i*4+2] = f2k(__float_as_uint(v.z));
        key[i*4+3] = f2k(__float_as_uint(v.w));
    }
    __syncthreads();  // counter zeroing complete

    // Invariant: count(key >= lo) >= k  AND  count(key >= hi) < k (hi = 2^32 counts 0).
    uint64_t lo = 0, hi = 1ull << 32;
    int r = 0;
    while ((hi - lo) > 1 && r < MAXR) {
        const uint64_t w  = hi - lo;
        const uint64_t a1 = lo + (w >> 1);          // mid (most informative first)
        const uint64_t q1 = lo + (w >> 2);
        const uint64_t q3 = lo + ((3ull * w) >> 2);
        const unsigned t1 = (unsigned)q1;
        const unsigned t2 = (unsigned)a1;
        const unsigned t3 = (unsigned)q3;

        unsigned long long c1 = 0, c2 = 0, c3 = 0;
#pragma unroll
        for (int e = 0; e < EPT; ++e) {
            c1 += (unsigned long long)__popcll(__ballot(key[e] >= t1));
            c2 += (unsigned long long)__popcll(__ballot(key[e] >= t2));
            c3 += (unsigned long long)__popcll(__ballot(key[e] >= t3));
        }
        if ((tid & 63) == 0)
            atomicAdd(&cnts[r], c1 + (c2 << 21) + (c3 << 42));
        __syncthreads();
        const unsigned long long tot = cnts[r];
        int cc1 = (int)(tot & 0x1FFFFFull);
        int cc2 = (int)((tot >> 21) & 0x1FFFFFull);
        int cc3 = (int)(tot >> 42);
        // counts are block-uniform; tell the compiler so lo/hi stay scalar
        cc1 = __builtin_amdgcn_readfirstlane(cc1);
        cc2 = __builtin_amdgcn_readfirstlane(cc2);
        cc3 = __builtin_amdgcn_readfirstlane(cc3);

        if (cc1 < k)      { hi = q1; }               // rank-k below q1
        else if (cc2 < k) { lo = q1; hi = a1; }
        else if (cc3 < k) { lo = a1; hi = q3; }
        else              { lo = q3; }
        ++r;
    }

    // lo is exactly the key of the k-th largest element.
    const unsigned tk = (unsigned)lo;
#pragma unroll
    for (int i = 0; i < F4PT; ++i) {
        float4 o;
        o.x = (key[i*4+0] >= tk) ? k2f(key[i*4+0]) : 0.0f;
        o.y = (key[i*4+1] >= tk) ? k2f(key[i*4+1]) : 0.0f;
        o.z = (key[i*4+2] >= tk) ? k2f(key[i*4+2]) : 0.0f;
        o.w = (key[i*4+3] >= tk) ? k2f(key[i*4+3]) : 0.0f;
        xout[i * TPB + tid] = o;
    }
}

extern "C" void kernel_launch(void* const* d_in, const int* in_sizes, int n_in,
                              void* d_out, int out_size, void* d_ws, size_t ws_size,
                              hipStream_t stream) {
    const float* x  = (const float*)d_in[0];
    const int*   kp = (const int*)d_in[1];
    float*       o  = (float*)d_out;
    const int rows = in_sizes[0] / COLS;
    topk_row_kernel<<<rows, TPB, 0, stream>>>(x, kp, o);
}

// Round 2
// 1321.716 us; speedup vs baseline: 1.0373x; 1.0373x over previous
//
#include <hip/hip_runtime.h>
#include <stdint.h>

#define COLS 16384
#define TPB 1024
#define NWAVES (TPB / 64)       // 16 waves per block
#define EPT (COLS / TPB)        // 16 elements per thread
#define F4PT (COLS / 4 / TPB)   // 4 float4 per thread
#define ROUNDS 16               // 4-way bisection: 2 bits/round x 16 = 32 bits exactly

// Order-preserving float -> u32 key map (monotone bijection over non-NaN).
__device__ __forceinline__ unsigned f2k(unsigned u) {
    return (u & 0x80000000u) ? ~u : (u | 0x80000000u);
}
__device__ __forceinline__ float k2f(unsigned kk) {
    unsigned u = (kk & 0x80000000u) ? (kk ^ 0x80000000u) : ~kk;
    return __uint_as_float(u);
}

__global__ __launch_bounds__(TPB, 8) void topk_row_kernel(
        const float* __restrict__ x,
        const int* __restrict__ kptr,
        float* __restrict__ out) {
    const int tid  = threadIdx.x;
    const int wid  = tid >> 6;
    const int lane = tid & 63;
    const size_t base = (size_t)blockIdx.x * (size_t)COLS;
    const float4* __restrict__ xin  = (const float4*)(x + base);
    float4*       __restrict__ xout = (float4*)(out + base);

    // Scalarize k: keeps the whole bisection control flow in SGPRs.
    const int k = __builtin_amdgcn_readfirstlane(kptr[0]);

    // Round-indexed per-wave slots: written once, read once, never reused ->
    // exactly ONE barrier per round, no zeroing, no atomics.
    __shared__ unsigned long long slot[ROUNDS * NWAVES];  // 2 KB

    // Load 16 elements/thread (coalesced float4), convert to sortable keys.
    unsigned key[EPT];
#pragma unroll
    for (int i = 0; i < F4PT; ++i) {
        float4 v = xin[i * TPB + tid];
        key[i*4+0] = f2k(__float_as_uint(v.x));
        key[i*4+1] = f2k(__float_as_uint(v.y));
        key[i*4+2] = f2k(__float_as_uint(v.z));
        key[i*4+3] = f2k(__float_as_uint(v.w));
    }

    // Invariant: count(key >= lo) >= k  AND  count(key >= hi) < k.
    uint64_t lo = 0, hi = 1ull << 32;
#pragma unroll 1
    for (int r = 0; r < ROUNDS; ++r) {
        const uint64_t w  = hi - lo;
        const uint64_t q1 = lo + (w >> 2);
        const uint64_t q2 = lo + (w >> 1);
        const uint64_t q3 = q1 + (w >> 1);
        const unsigned t1 = (unsigned)q1;
        const unsigned t2 = (unsigned)q2;
        const unsigned t3 = (unsigned)q3;

        // Per-wave counts: v_cmp (vector) + s_bcnt1/s_add (scalar).
        unsigned c1 = 0, c2 = 0, c3 = 0;
#pragma unroll
        for (int e = 0; e < EPT; ++e) {
            c1 += (unsigned)__popcll(__ballot(key[e] >= t1));
            c2 += (unsigned)__popcll(__ballot(key[e] >= t2));
            c3 += (unsigned)__popcll(__ballot(key[e] >= t3));
        }
        if (lane == 0)
            slot[r * NWAVES + wid] =
                (unsigned long long)c1 |
                ((unsigned long long)c2 << 21) |
                ((unsigned long long)c3 << 42);
        __syncthreads();

        // Lane-parallel combine: lane i reads slot (i&15), butterfly-sum the
        // 16-lane groups, then every lane holds the block total.
        unsigned long long s = slot[r * NWAVES + (lane & (NWAVES - 1))];
        s += __shfl_xor(s, 1);
        s += __shfl_xor(s, 2);
        s += __shfl_xor(s, 4);
        s += __shfl_xor(s, 8);
        const int cc1 = __builtin_amdgcn_readfirstlane((int)(s & 0x1FFFFFull));
        const int cc2 = __builtin_amdgcn_readfirstlane((int)((s >> 21) & 0x1FFFFFull));
        const int cc3 = __builtin_amdgcn_readfirstlane((int)(s >> 42));

        if (cc1 < k)      { hi = q1; }
        else if (cc2 < k) { lo = q1; hi = q2; }
        else if (cc3 < k) { lo = q2; hi = q3; }
        else              { lo = q3; }
    }

    // After 16 rounds hi-lo == 1: lo is exactly the k-th largest key.
    const unsigned tk = (unsigned)lo;
#pragma unroll
    for (int i = 0; i < F4PT; ++i) {
        float4 o;
        o.x = (key[i*4+0] >= tk) ? k2f(key[i*4+0]) : 0.0f;
        o.y = (key[i*4+1] >= tk) ? k2f(key[i*4+1]) : 0.0f;
        o.z = (key[i*4+2] >= tk) ? k2f(key[i*4+2]) : 0.0f;
        o.w = (key[i*4+3] >= tk) ? k2f(key[i*4+3]) : 0.0f;
        xout[i * TPB + tid] = o;
    }
}

extern "C" void kernel_launch(void* const* d_in, const int* in_sizes, int n_in,
                              void* d_out, int out_size, void* d_ws, size_t ws_size,
                              hipStream_t stream) {
    const float* x  = (const float*)d_in[0];
    const int*   kp = (const int*)d_in[1];
    float*       o  = (float*)d_out;
    const int rows = in_sizes[0] / COLS;
    topk_row_kernel<<<rows, TPB, 0, stream>>>(x, kp, o);
}

// Round 3
// 1187.903 us; speedup vs baseline: 1.1542x; 1.1126x over previous
//
#include <hip/hip_runtime.h>
#include <stdint.h>

#define COLS 16384
#define TPB 1024
#define NWAVES 16               // 16 waves per block
#define EPT 16                  // elements per thread
#define F4PT 4                  // float4 per thread
#define ROUNDS 16               // 4-way bisection: 2 bits x 16 = 32 bits exactly

// Order-preserving float -> u32 key map (monotone bijection over non-NaN).
__device__ __forceinline__ unsigned f2k(unsigned u) {
    return (u & 0x80000000u) ? ~u : (u | 0x80000000u);
}

// Scalar popcount of a ballot mask: stays entirely in the SALU pipe.
__device__ __forceinline__ unsigned sbcnt(unsigned long long m) {
    unsigned c;
    asm("s_bcnt1_i32_b64 %0, %1" : "=s"(c) : "s"(m) : "scc");
    return c;
}

__global__ __launch_bounds__(TPB, 8) void topk_row_kernel(
        const float* __restrict__ x,
        const int* __restrict__ kptr,
        float* __restrict__ out) {
    const int tid  = threadIdx.x;
    const int wid  = tid >> 6;
    const int lane = tid & 63;
    const size_t base = (size_t)blockIdx.x * (size_t)COLS;
    const float4* __restrict__ xin  = (const float4*)(x + base);
    float4*       __restrict__ xout = (float4*)(out + base);

    const int k = __builtin_amdgcn_readfirstlane(kptr[0]);

    // Round-indexed per-wave slots: one barrier per round, no zeroing/atomics.
    __shared__ unsigned long long slot[ROUNDS * NWAVES];  // 2 KB

    // Load 16 elems/thread (coalesced float4); keep BOTH floats and keys in
    // registers so the epilogue needs no back-conversion.
    float4 v[F4PT];
    unsigned key[EPT];
#pragma unroll
    for (int i = 0; i < F4PT; ++i) {
        v[i] = xin[i * TPB + tid];
        key[i*4+0] = f2k(__float_as_uint(v[i].x));
        key[i*4+1] = f2k(__float_as_uint(v[i].y));
        key[i*4+2] = f2k(__float_as_uint(v[i].z));
        key[i*4+3] = f2k(__float_as_uint(v[i].w));
    }

    // Invariant: count(key >= lo) >= k  AND  count(key >= hi) < k.
    uint64_t lo = 0, hi = 1ull << 32;
#pragma unroll 1
    for (int r = 0; r < ROUNDS; ++r) {
        const uint64_t w  = hi - lo;
        const uint64_t q1 = lo + (w >> 2);
        const uint64_t q2 = lo + (w >> 1);
        const uint64_t q3 = q1 + (w >> 1);
        const unsigned t1 = (unsigned)q1;
        const unsigned t2 = (unsigned)q2;
        const unsigned t3 = (unsigned)q3;

        // 1 VALU (v_cmp -> sgpr pair) + 1 SALU (s_bcnt1) per compare;
        // accumulators live in SGPRs.
        unsigned c1 = 0, c2 = 0, c3 = 0;
#pragma unroll
        for (int e = 0; e < EPT; ++e) {
            c1 += sbcnt(__builtin_amdgcn_ballot_w64(key[e] >= t1));
            c2 += sbcnt(__builtin_amdgcn_ballot_w64(key[e] >= t2));
            c3 += sbcnt(__builtin_amdgcn_ballot_w64(key[e] >= t3));
        }
        if (lane == 0)
            slot[r * NWAVES + wid] =
                (unsigned long long)c1 |
                ((unsigned long long)c2 << 21) |
                ((unsigned long long)c3 << 42);
        __syncthreads();

        // Lane-parallel combine: lane i reads slot (i&15), butterfly over the
        // 16-lane group, then broadcast.
        unsigned long long s = slot[r * NWAVES + (lane & (NWAVES - 1))];
        s += __shfl_xor(s, 1);
        s += __shfl_xor(s, 2);
        s += __shfl_xor(s, 4);
        s += __shfl_xor(s, 8);
        const int cc1 = __builtin_amdgcn_readfirstlane((int)(s & 0x1FFFFFull));
        const int cc2 = __builtin_amdgcn_readfirstlane((int)((s >> 21) & 0x1FFFFFull));
        const int cc3 = __builtin_amdgcn_readfirstlane((int)(s >> 42));

        if (cc1 < k)      { hi = q1; }
        else if (cc2 < k) { lo = q1; hi = q2; }
        else if (cc3 < k) { lo = q2; hi = q3; }
        else              { lo = q3; }
    }

    // After 16 rounds hi-lo == 1: lo is exactly the k-th largest key.
    const unsigned tk = (unsigned)lo;
#pragma unroll
    for (int i = 0; i < F4PT; ++i) {
        float4 o;
        o.x = (key[i*4+0] >= tk) ? v[i].x : 0.0f;
        o.y = (key[i*4+1] >= tk) ? v[i].y : 0.0f;
        o.z = (key[i*4+2] >= tk) ? v[i].z : 0.0f;
        o.w = (key[i*4+3] >= tk) ? v[i].w : 0.0f;
        xout[i * TPB + tid] = o;
    }
}

extern "C" void kernel_launch(void* const* d_in, const int* in_sizes, int n_in,
                              void* d_out, int out_size, void* d_ws, size_t ws_size,
                              hipStream_t stream) {
    const float* x  = (const float*)d_in[0];
    const int*   kp = (const int*)d_in[1];
    float*       o  = (float*)d_out;
    const int rows = in_sizes[0] / COLS;
    topk_row_kernel<<<rows, TPB, 0, stream>>>(x, kp, o);
}